// Round 9
// baseline (155.261 us; speedup 1.0000x reference)
//
#include <hip/hip_runtime.h>
#include <math.h>

#define B 4
#define S 4096
#define DIN 1024
#define DOUT 64
#define BS (B * S)

typedef __bf16 bf16;
typedef __bf16 bf16x4 __attribute__((ext_vector_type(4)));
typedef __bf16 bf16x8 __attribute__((ext_vector_type(8)));
typedef float f32x4 __attribute__((ext_vector_type(4)));

// log2(e)/64: folds the 1/sqrt(S)=1/64 score scale and exp->exp2 into Q.
#define QSCALE 0.022542110013890053f

// Workspace layout (bytes), ~23.5 MB of the 256 MiB ws:
//   Qs : 0      [BS][64] bf16 (pre-scaled by log2e/64), row-major
//   KF : 2 MB   QK^T B-fragment order: [tile 256][nt 4][c 2][lane 64][j 8] bf16
//   VF : 4 MB   PV  B-fragment order: [tile 256][c 2][ntd 4][lane 64][j 8] bf16
//   WP : 6 MB   [12][32][64][8] bf16 (projection B-fragment order)
//   OP : 7 MB   [4096 slots][32 q][64 d] bf16  unnormalized eighth-partial O
//   LP : 23 MB  [4096 slots][32 q] f32         eighth-partial row sums
#define QS_OFF 0
#define KF_OFF (2u * 1024 * 1024)
#define VF_OFF (4u * 1024 * 1024)
#define WP_OFF (6u * 1024 * 1024)
#define OP_OFF (7u * 1024 * 1024)
#define LP_OFF (23u * 1024 * 1024)

// ---------------------------------------------------------------------------
// W repack, COALESCED reads, scattered fire-and-forget bf16 stores.
// wp[((nt*32+kc)*64 + lane)*8 + j] = W[k][n],
//   k = kc*32 + (lane>>4)*8 + j, n = nt*16 + (lane&15).
// ---------------------------------------------------------------------------
__global__ __launch_bounds__(256) void wpack_kernel(
    const float* __restrict__ Wq, const float* __restrict__ Wk,
    const float* __restrict__ Wv, bf16* __restrict__ wp) {
  const int t = blockIdx.x * 256 + threadIdx.x;  // [0, 196608)
  const int m = t >> 16;                         // 0=Q 1=K 2=V
  const int r = t & 65535;                       // k*64 + n64
  const int k = r >> 6;
  const int n64 = r & 63;
  const float* W = (m == 0) ? Wq : (m == 1) ? Wk : Wv;
  const float v = W[r];                          // coalesced
  const int n = m * 64 + n64;
  const int nt = n >> 4;
  const int lane = ((k >> 3) & 3) * 16 + (n & 15);
  const int idx = ((nt * 32 + (k >> 5)) * 64 + lane) * 8 + (k & 7);
  wp[idx] = (bf16)v;
}

// ---------------------------------------------------------------------------
// QKV projection, MFMA 16x16x32 bf16, SEL-SPLIT for concurrency.
// Block = (32 rows, sel in {Q,K,V}) -> grid 1536 = 6 blocks/CU, 24 waves/CU
// (round 8 had 8 waves/CU and was latency-dead at 19% occupancy).  Each
// block reads ONLY its sel's 128 KB wp slice (wp L2 traffic unchanged);
// x re-read 3x is L3-absorbed.  Wave = 1 nt x 2 strips x full K.
// LDS: round-6's proven conflict-free tile (32 x 136 bf16, double-buffered
// 4-kc phases, 17.4 KB -> all 6 blocks resident); 4 float4 prefetched per
// phase per thread.  Epilogue identical to round 8 (fragment-order K/V).
// ---------------------------------------------------------------------------
__global__ __launch_bounds__(256, 6) void qkv_mfma_kernel(
    const float* __restrict__ x, const float* __restrict__ bq,
    const float* __restrict__ bk, const float* __restrict__ bv,
    const bf16* __restrict__ wp, bf16* __restrict__ Qs,
    bf16* __restrict__ KF, bf16* __restrict__ VF) {
  __shared__ __align__(16) bf16 xt[2][32][136];  // 17408 B

  const int tid = threadIdx.x;
  const int wid = tid >> 6;
  const int lane = tid & 63;
  const int l15 = lane & 15;
  const int quad = lane >> 4;
  const int sel = blockIdx.x % 3;        // 0=Q 1=K 2=V
  const int blk = blockIdx.x / 3;        // rows [blk*32, blk*32+32)
  const int nt = sel * 4 + wid;          // this wave's global n-tile

  const int srow = tid >> 3;             // staging row 0..31
  const int sc4 = tid & 7;               // float4 index within 32-col group
  const float* xrow = x + (size_t)(blk * 32 + srow) * DIN + sc4 * 4;
  const bf16x8* wp8 = (const bf16x8*)wp;

  f32x4 acc[2] = {(f32x4)(0.f), (f32x4)(0.f)};

  // prologue: stage phase 0 (cols 0..127) into buf 0
  {
    float4 pf[4];
#pragma unroll
    for (int i = 0; i < 4; ++i) pf[i] = *(const float4*)(xrow + i * 32);
#pragma unroll
    for (int i = 0; i < 4; ++i) {
      bf16x4 c;
      c[0] = (bf16)pf[i].x; c[1] = (bf16)pf[i].y;
      c[2] = (bf16)pf[i].z; c[3] = (bf16)pf[i].w;
      *(bf16x4*)&xt[0][srow][i * 32 + sc4 * 4] = c;
    }
  }
  __syncthreads();

  for (int p = 0; p < 8; ++p) {
    const int buf = p & 1;
    // issue next phase's 4 global loads (land during compute)
    float4 pf[4];
    if (p < 7) {
#pragma unroll
      for (int i = 0; i < 4; ++i)
        pf[i] = *(const float4*)(xrow + (p + 1) * 128 + i * 32);
    }
    // compute 4 kc from xt[buf]
#pragma unroll
    for (int i = 0; i < 4; ++i) {
      const int kc = p * 4 + i;
      const bf16x8 bfr = wp8[(nt * 32 + kc) * 64 + lane];
      const bf16x8 a0 = *(const bf16x8*)&xt[buf][l15][i * 32 + quad * 8];
      const bf16x8 a1 = *(const bf16x8*)&xt[buf][16 + l15][i * 32 + quad * 8];
      acc[0] = __builtin_amdgcn_mfma_f32_16x16x32_bf16(a0, bfr, acc[0], 0, 0, 0);
      acc[1] = __builtin_amdgcn_mfma_f32_16x16x32_bf16(a1, bfr, acc[1], 0, 0, 0);
    }
    if (p < 7) {
      __syncthreads();  // all waves done reading buf^1 (their phase p-1)
#pragma unroll
      for (int i = 0; i < 4; ++i) {
        bf16x4 c;
        c[0] = (bf16)pf[i].x; c[1] = (bf16)pf[i].y;
        c[2] = (bf16)pf[i].z; c[3] = (bf16)pf[i].w;
        *(bf16x4*)&xt[buf ^ 1][srow][i * 32 + sc4 * 4] = c;
      }
      __syncthreads();  // staged for phase p+1
    }
  }

  // epilogue (round-8 formulas verbatim; sel is block-uniform)
  const int c = wid * 16 + l15;  // output column within this sel's 64
  const float bias = ((sel == 0) ? bq : (sel == 1) ? bk : bv)[c];
#pragma unroll
  for (int st = 0; st < 2; ++st) {
    const int row0 = blk * 32 + st * 16 + quad * 4;  // 4 consecutive rows
    if (sel == 0) {
#pragma unroll
      for (int r = 0; r < 4; ++r)
        Qs[(size_t)(row0 + r) * DOUT + c] =
            (bf16)((acc[st][r] + bias) * QSCALE);
    } else if (sel == 1) {
      const size_t kb =
          ((size_t)(((row0 >> 6) * 4 + ((row0 >> 4) & 3)) * 2 + (c >> 5)) * 64 +
           ((c >> 3) & 3) * 16 + quad * 4) * 8 + (c & 7);
#pragma unroll
      for (int r = 0; r < 4; ++r)
        KF[kb + r * 8] = (bf16)(acc[st][r] + bias);
    } else {
      const size_t vb =
          ((size_t)(((row0 >> 6) * 2 + ((row0 >> 5) & 1)) * 4 + (c >> 4)) * 64 +
           (c & 15) + 16 * ((row0 >> 3) & 3)) * 8 + (row0 & 7);
      bf16x4 vv;
#pragma unroll
      for (int r = 0; r < 4; ++r) vv[r] = (bf16)(acc[st][r] + bias);
      *(bf16x4*)(VF + vb) = vv;
    }
  }
}

// ---------------------------------------------------------------------------
// Flash attention, MFMA 16x16x32 bf16, fragment-direct + SOFTWARE PIPELINE.
// Block = (batch, 32-row strip, key-half); 4 waves = key-eighths, fully
// independent (no __syncthreads).  Per tile: vf loads at top (covered by
// QK+exp), per-nt QK->exp (short s lifetime), then kf for tile t+1 is
// prefetched into the SAME kf registers (their last use was the nt loop)
// during exp/PV -> the 250-cyc L2 latency is hidden with zero VGPR growth.
// Eighth-partials (O bf16, l f32) to ws; combine finishes.
// ---------------------------------------------------------------------------
__global__ __launch_bounds__(256, 3) void attn_mfma_kernel(
    const bf16* __restrict__ Qs, const bf16* __restrict__ KFp,
    const bf16* __restrict__ VFp, bf16* __restrict__ Oh,
    float* __restrict__ lh) {
  __shared__ __align__(16) bf16 pw[4][32][72];  // 18432 B, per-wave regions

  const int tid = threadIdx.x;
  const int wid = tid >> 6;
  const int lane = tid & 63;
  const int l15 = lane & 15;
  const int quad = lane >> 4;
  const int b = blockIdx.x & 3;                // XCD affinity by batch
  const int half = (blockIdx.x >> 2) & 1;
  const int s32 = 127 - (blockIdx.x >> 3);     // LPT: longest first
  const int ntiles = (s32 >> 1) + 1;
  const int e = half * 4 + wid;                // eighth 0..7
  const int t0 = (e * ntiles) >> 3;
  const int t1 = ((e + 1) * ntiles) >> 3;

  const bf16x8* KF8 = (const bf16x8*)KFp;
  const bf16x8* VF8 = (const bf16x8*)VFp;
  const int tb0 = b * 64;

  const bf16* Qb = Qs + ((size_t)b * S + s32 * 32) * DOUT;
  bf16x8 qf[2][2];
#pragma unroll
  for (int st = 0; st < 2; ++st)
#pragma unroll
    for (int k = 0; k < 2; ++k)
      qf[st][k] =
          *(const bf16x8*)(Qb + (st * 16 + l15) * DOUT + k * 32 + quad * 8);

  f32x4 o[2][4];
#pragma unroll
  for (int st = 0; st < 2; ++st)
#pragma unroll
    for (int i = 0; i < 4; ++i) o[st][i] = (f32x4)(0.f);
  f32x4 lsum[2] = {(f32x4)(0.f), (f32x4)(0.f)};

  // prologue: kf for the first tile
  bf16x8 kf[8];
  if (t0 < t1) {
    const int tb = tb0 + t0;
#pragma unroll
    for (int nt = 0; nt < 4; ++nt)
#pragma unroll
      for (int c = 0; c < 2; ++c)
        kf[nt * 2 + c] = KF8[(size_t)((tb * 4 + nt) * 2 + c) * 64 + lane];
  }

  for (int t = t0; t < t1; ++t) {
    const int tb = tb0 + t;
    // vf loads (consumed after QK+exp -> latency covered)
    bf16x8 vf[8];
#pragma unroll
    for (int c = 0; c < 2; ++c)
#pragma unroll
      for (int ntd = 0; ntd < 4; ++ntd)
        vf[c * 4 + ntd] = VF8[(size_t)((tb * 2 + c) * 4 + ntd) * 64 + lane];

    // per-nt QK -> exp -> pw (klim trick: non-diag tiles never mask)
    const int klim = (t == ntiles - 1) ? 0 : (1 << 24);
#pragma unroll
    for (int nt = 0; nt < 4; ++nt) {
      f32x4 s0 = __builtin_amdgcn_mfma_f32_16x16x32_bf16(
          qf[0][0], kf[nt * 2 + 0], (f32x4)(0.f), 0, 0, 0);
      s0 = __builtin_amdgcn_mfma_f32_16x16x32_bf16(qf[0][1], kf[nt * 2 + 1],
                                                   s0, 0, 0, 0);
      f32x4 s1 = __builtin_amdgcn_mfma_f32_16x16x32_bf16(
          qf[1][0], kf[nt * 2 + 0], (f32x4)(0.f), 0, 0, 0);
      s1 = __builtin_amdgcn_mfma_f32_16x16x32_bf16(qf[1][1], kf[nt * 2 + 1],
                                                   s1, 0, 0, 0);
      const int key = t * 64 + nt * 16 + l15;
#pragma unroll
      for (int r = 0; r < 4; ++r) {
        const int q0 = s32 * 32 + quad * 4 + r + klim;
        const float p0 = (key <= q0) ? exp2f(fminf(s0[r], 44.f)) : 0.f;
        lsum[0][r] += p0;
        pw[wid][quad * 4 + r][nt * 16 + l15] = (bf16)p0;
        const float p1 = (key <= q0 + 16) ? exp2f(fminf(s1[r], 44.f)) : 0.f;
        lsum[1][r] += p1;
        pw[wid][16 + quad * 4 + r][nt * 16 + l15] = (bf16)p1;
      }
    }

    // prefetch next tile's kf into the same regs (last use was above)
    if (t + 1 < t1) {
      const int tbn = tb + 1;
#pragma unroll
      for (int nt = 0; nt < 4; ++nt)
#pragma unroll
        for (int c = 0; c < 2; ++c)
          kf[nt * 2 + c] = KF8[(size_t)((tbn * 4 + nt) * 2 + c) * 64 + lane];
    }

    // P C->A round-trip (same-wave LDS; lgkmcnt orders it), then PV
#pragma unroll
    for (int st = 0; st < 2; ++st) {
      const bf16x8 pf0 = *(const bf16x8*)&pw[wid][st * 16 + l15][quad * 8];
      const bf16x8 pf1 = *(const bf16x8*)&pw[wid][st * 16 + l15][32 + quad * 8];
#pragma unroll
      for (int ntd = 0; ntd < 4; ++ntd) {
        o[st][ntd] = __builtin_amdgcn_mfma_f32_16x16x32_bf16(
            pf0, vf[0 * 4 + ntd], o[st][ntd], 0, 0, 0);
        o[st][ntd] = __builtin_amdgcn_mfma_f32_16x16x32_bf16(
            pf1, vf[1 * 4 + ntd], o[st][ntd], 0, 0, 0);
      }
    }
  }

  // row sums across the 16 lanes of each quad
#pragma unroll
  for (int m = 1; m < 16; m <<= 1)
#pragma unroll
    for (int st = 0; st < 2; ++st)
#pragma unroll
      for (int r = 0; r < 4; ++r) lsum[st][r] += __shfl_xor(lsum[st][r], m, 64);

  const int slot = (b * 128 + s32) * 8 + e;
  if (l15 == 0) {
#pragma unroll
    for (int st = 0; st < 2; ++st)
#pragma unroll
      for (int r = 0; r < 4; ++r)
        lh[slot * 32 + st * 16 + quad * 4 + r] = lsum[st][r];
  }
#pragma unroll
  for (int st = 0; st < 2; ++st)
#pragma unroll
    for (int ntd = 0; ntd < 4; ++ntd)
#pragma unroll
      for (int r = 0; r < 4; ++r)
        Oh[(size_t)slot * 2048 + (st * 16 + quad * 4 + r) * 64 + ntd * 16 + l15] =
            (bf16)o[st][ntd][r];
}

// ---------------------------------------------------------------------------
// Sum the 8 eighth-partials and normalize.  262144 f32x4 -> grid 1024x256.
// ---------------------------------------------------------------------------
__global__ __launch_bounds__(256) void combine_kernel(
    const bf16* __restrict__ Oh, const float* __restrict__ lh,
    float* __restrict__ out) {
  const int gid = blockIdx.x * 256 + threadIdx.x;  // [0, 262144)
  const int token = gid >> 4;                      // 0..16383
  const int d4 = (gid & 15) * 4;
  const int b = token >> 12;
  const int s = token & 4095;
  const int s32 = s >> 5;
  const int qq = s & 31;
  const int slot0 = (b * 128 + s32) * 8;
  f32x4 acc = (f32x4)(0.f);
  float l = 0.f;
#pragma unroll
  for (int q = 0; q < 8; ++q) {
    const bf16x4 ov =
        *(const bf16x4*)(Oh + (size_t)(slot0 + q) * 2048 + qq * 64 + d4);
#pragma unroll
    for (int i = 0; i < 4; ++i) acc[i] += (float)ov[i];
    l += lh[(slot0 + q) * 32 + qq];
  }
  ((f32x4*)out)[gid] = acc * (1.f / l);
}

// ---------------------------------------------------------------------------
extern "C" void kernel_launch(void* const* d_in, const int* in_sizes, int n_in,
                              void* d_out, int out_size, void* d_ws,
                              size_t ws_size, hipStream_t stream) {
  const float* x  = (const float*)d_in[0];
  const float* Wq = (const float*)d_in[1];
  const float* bq = (const float*)d_in[2];
  const float* Wk = (const float*)d_in[3];
  const float* bk = (const float*)d_in[4];
  const float* Wv = (const float*)d_in[5];
  const float* bv = (const float*)d_in[6];
  float* out = (float*)d_out;

  char* ws = (char*)d_ws;
  bf16* Qs = (bf16*)(ws + QS_OFF);
  bf16* KF = (bf16*)(ws + KF_OFF);
  bf16* VF = (bf16*)(ws + VF_OFF);
  bf16* wp = (bf16*)(ws + WP_OFF);
  bf16* Oh = (bf16*)(ws + OP_OFF);
  float* lh = (float*)(ws + LP_OFF);

  wpack_kernel<<<768, 256, 0, stream>>>(Wq, Wk, Wv, wp);
  qkv_mfma_kernel<<<1536, 256, 0, stream>>>(x, bq, bk, bv, wp, Qs, KF, VF);
  attn_mfma_kernel<<<1024, 256, 0, stream>>>(Qs, KF, VF, Oh, lh);
  combine_kernel<<<1024, 256, 0, stream>>>(Oh, lh, out);
}

// Round 10
// 151.552 us; speedup vs baseline: 1.0245x; 1.0245x over previous
//
#include <hip/hip_runtime.h>
#include <math.h>

#define B 4
#define S 4096
#define DIN 1024
#define DOUT 64
#define BS (B * S)

typedef __bf16 bf16;
typedef __bf16 bf16x4 __attribute__((ext_vector_type(4)));
typedef __bf16 bf16x8 __attribute__((ext_vector_type(8)));
typedef float f32x4 __attribute__((ext_vector_type(4)));

// log2(e)/64: folds the 1/sqrt(S)=1/64 score scale and exp->exp2 into Q.
#define QSCALE 0.022542110013890053f

// Workspace layout (bytes), ~23.5 MB of the 256 MiB ws:
//   Qs : 0      [BS][64] bf16 (pre-scaled by log2e/64), row-major
//   KF : 2 MB   QK^T B-fragment order: [tile 256][nt 4][c 2][lane 64][j 8] bf16
//   VF : 4 MB   PV  B-fragment order: [tile 256][c 2][ntd 4][lane 64][j 8] bf16
//   WP : 6 MB   [12][32][64][8] bf16 (projection B-fragment order)
//   OP : 7 MB   [4096 slots][32 q][64 d] bf16  unnormalized eighth-partial O
//   LP : 23 MB  [4096 slots][32 q] f32         eighth-partial row sums
#define QS_OFF 0
#define KF_OFF (2u * 1024 * 1024)
#define VF_OFF (4u * 1024 * 1024)
#define WP_OFF (6u * 1024 * 1024)
#define OP_OFF (7u * 1024 * 1024)
#define LP_OFF (23u * 1024 * 1024)

// ---------------------------------------------------------------------------
// W repack, COALESCED reads, scattered fire-and-forget bf16 stores.
// wp[((nt*32+kc)*64 + lane)*8 + j] = W[k][n],
//   k = kc*32 + (lane>>4)*8 + j, n = nt*16 + (lane&15).
// ---------------------------------------------------------------------------
__global__ __launch_bounds__(256) void wpack_kernel(
    const float* __restrict__ Wq, const float* __restrict__ Wk,
    const float* __restrict__ Wv, bf16* __restrict__ wp) {
  const int t = blockIdx.x * 256 + threadIdx.x;  // [0, 196608)
  const int m = t >> 16;                         // 0=Q 1=K 2=V
  const int r = t & 65535;                       // k*64 + n64
  const int k = r >> 6;
  const int n64 = r & 63;
  const float* W = (m == 0) ? Wq : (m == 1) ? Wk : Wv;
  const float v = W[r];                          // coalesced
  const int n = m * 64 + n64;
  const int nt = n >> 4;
  const int lane = ((k >> 3) & 3) * 16 + (n & 15);
  const int idx = ((nt * 32 + (k >> 5)) * 64 + lane) * 8 + (k & 7);
  wp[idx] = (bf16)v;
}

// ---------------------------------------------------------------------------
// QKV projection, MFMA 16x16x32 bf16, 16-ROW BLOCKS for cross-block overlap.
// Grid 1024 = 4 blocks/CU, 16 waves/CU; x read EXACTLY ONCE (the R9
// sel-split read it 3x and regressed).  Block = 16 rows; wave w owns nt in
// [3w, 3w+3) x full K -> complete accumulators, 3 f32x4 acc (low VGPR).
// x staged fp32->bf16 through a double-buffered 256-col LDS phase tile
// (16.9 KB -> all 4 blocks resident); 4 burst float4/thread per phase with
// next-phase loads issued into registers BEFORE compute.  8 barriers total.
// When one block drains its barrier, 3 sibling blocks keep the CU busy.
// Epilogue: Q row-major, K/V directly in attention B-fragment order.
// ---------------------------------------------------------------------------
__global__ __launch_bounds__(256, 4) void qkv_mfma_kernel(
    const float* __restrict__ x, const float* __restrict__ bq,
    const float* __restrict__ bk, const float* __restrict__ bv,
    const bf16* __restrict__ wp, bf16* __restrict__ Qs,
    bf16* __restrict__ KF, bf16* __restrict__ VF) {
  __shared__ __align__(16) bf16 xt[2][16][264];  // 16896 B

  const int tid = threadIdx.x;
  const int wid = tid >> 6;
  const int lane = tid & 63;
  const int l15 = lane & 15;
  const int quad = lane >> 4;
  const int blk = blockIdx.x;  // rows [blk*16, blk*16+16)

  const bf16x8* wp8 = (const bf16x8*)wp;

  f32x4 acc[3];
#pragma unroll
  for (int j = 0; j < 3; ++j) acc[j] = (f32x4)(0.f);

  // staging map: i-th chunk -> row i*4+wid, cols lane*4..lane*4+3 (coalesced:
  // 64 lanes x 16 B = 1 KB contiguous per row)
  const float* xb = x + (size_t)blk * 16 * DIN;

  // prologue: stage phase 0 (cols 0..255) into buf 0
  {
    float4 v[4];
#pragma unroll
    for (int i = 0; i < 4; ++i)
      v[i] = *(const float4*)(xb + (size_t)(i * 4 + wid) * DIN + lane * 4);
#pragma unroll
    for (int i = 0; i < 4; ++i) {
      bf16x4 c;
      c[0] = (bf16)v[i].x; c[1] = (bf16)v[i].y;
      c[2] = (bf16)v[i].z; c[3] = (bf16)v[i].w;
      *(bf16x4*)&xt[0][i * 4 + wid][lane * 4] = c;
    }
  }
  __syncthreads();

  for (int p = 0; p < 4; ++p) {
    const int buf = p & 1;
    // issue next phase's 4 global loads (land during compute)
    float4 v[4];
    if (p < 3) {
#pragma unroll
      for (int i = 0; i < 4; ++i)
        v[i] = *(const float4*)(xb + (size_t)(i * 4 + wid) * DIN +
                                (p + 1) * 256 + lane * 4);
    }
    // compute 8 kc from xt[buf]
#pragma unroll
    for (int i = 0; i < 8; ++i) {
      const int kc = p * 8 + i;
      bf16x8 bfr[3];
#pragma unroll
      for (int j = 0; j < 3; ++j)
        bfr[j] = wp8[((wid * 3 + j) * 32 + kc) * 64 + lane];
      const bf16x8 a = *(const bf16x8*)&xt[buf][l15][i * 32 + quad * 8];
#pragma unroll
      for (int j = 0; j < 3; ++j)
        acc[j] = __builtin_amdgcn_mfma_f32_16x16x32_bf16(a, bfr[j], acc[j], 0, 0, 0);
    }
    if (p < 3) {
      __syncthreads();  // all waves done reading buf^1 (their phase p-1)
#pragma unroll
      for (int i = 0; i < 4; ++i) {
        bf16x4 c;
        c[0] = (bf16)v[i].x; c[1] = (bf16)v[i].y;
        c[2] = (bf16)v[i].z; c[3] = (bf16)v[i].w;
        *(bf16x4*)&xt[buf ^ 1][i * 4 + wid][lane * 4] = c;
      }
      __syncthreads();  // staged for phase p+1
    }
  }

  // epilogue: 3 nt per wave, 16 rows (row0 = blk*16 + quad*4)
#pragma unroll
  for (int j = 0; j < 3; ++j) {
    const int nt = wid * 3 + j;
    const int sel = nt >> 2;             // 0=Q 1=K 2=V (wave-uniform)
    const int c = (nt & 3) * 16 + l15;   // output column (d)
    const float bias = ((sel == 0) ? bq : (sel == 1) ? bk : bv)[c];
    const int row0 = blk * 16 + quad * 4;  // 4 consecutive rows
    if (sel == 0) {
#pragma unroll
      for (int r = 0; r < 4; ++r)
        Qs[(size_t)(row0 + r) * DOUT + c] =
            (bf16)((acc[j][r] + bias) * QSCALE);
    } else if (sel == 1) {
      const size_t kb =
          ((size_t)(((row0 >> 6) * 4 + ((row0 >> 4) & 3)) * 2 + (c >> 5)) * 64 +
           ((c >> 3) & 3) * 16 + quad * 4) * 8 + (c & 7);
#pragma unroll
      for (int r = 0; r < 4; ++r)
        KF[kb + r * 8] = (bf16)(acc[j][r] + bias);
    } else {
      const size_t vb =
          ((size_t)(((row0 >> 6) * 2 + ((row0 >> 5) & 1)) * 4 + (c >> 4)) * 64 +
           (c & 15) + 16 * ((row0 >> 3) & 3)) * 8 + (row0 & 7);
      bf16x4 vv;
#pragma unroll
      for (int r = 0; r < 4; ++r) vv[r] = (bf16)(acc[j][r] + bias);
      *(bf16x4*)(VF + vb) = vv;
    }
  }
}

// ---------------------------------------------------------------------------
// Flash attention, MFMA 16x16x32 bf16, fragment-direct + SOFTWARE PIPELINE.
// Block = (batch, 32-row strip, key-half); 4 waves = key-eighths, fully
// independent (no __syncthreads).  Per tile: vf loads at top (covered by
// QK+exp), per-nt QK->exp (short s lifetime), then kf for tile t+1 is
// prefetched into the SAME kf registers during exp/PV.  Eighth-partials
// (O bf16, l f32) to ws; combine finishes.  (Unchanged from round 9.)
// ---------------------------------------------------------------------------
__global__ __launch_bounds__(256, 3) void attn_mfma_kernel(
    const bf16* __restrict__ Qs, const bf16* __restrict__ KFp,
    const bf16* __restrict__ VFp, bf16* __restrict__ Oh,
    float* __restrict__ lh) {
  __shared__ __align__(16) bf16 pw[4][32][72];  // 18432 B, per-wave regions

  const int tid = threadIdx.x;
  const int wid = tid >> 6;
  const int lane = tid & 63;
  const int l15 = lane & 15;
  const int quad = lane >> 4;
  const int b = blockIdx.x & 3;                // XCD affinity by batch
  const int half = (blockIdx.x >> 2) & 1;
  const int s32 = 127 - (blockIdx.x >> 3);     // LPT: longest first
  const int ntiles = (s32 >> 1) + 1;
  const int e = half * 4 + wid;                // eighth 0..7
  const int t0 = (e * ntiles) >> 3;
  const int t1 = ((e + 1) * ntiles) >> 3;

  const bf16x8* KF8 = (const bf16x8*)KFp;
  const bf16x8* VF8 = (const bf16x8*)VFp;
  const int tb0 = b * 64;

  const bf16* Qb = Qs + ((size_t)b * S + s32 * 32) * DOUT;
  bf16x8 qf[2][2];
#pragma unroll
  for (int st = 0; st < 2; ++st)
#pragma unroll
    for (int k = 0; k < 2; ++k)
      qf[st][k] =
          *(const bf16x8*)(Qb + (st * 16 + l15) * DOUT + k * 32 + quad * 8);

  f32x4 o[2][4];
#pragma unroll
  for (int st = 0; st < 2; ++st)
#pragma unroll
    for (int i = 0; i < 4; ++i) o[st][i] = (f32x4)(0.f);
  f32x4 lsum[2] = {(f32x4)(0.f), (f32x4)(0.f)};

  // prologue: kf for the first tile
  bf16x8 kf[8];
  if (t0 < t1) {
    const int tb = tb0 + t0;
#pragma unroll
    for (int nt = 0; nt < 4; ++nt)
#pragma unroll
      for (int c = 0; c < 2; ++c)
        kf[nt * 2 + c] = KF8[(size_t)((tb * 4 + nt) * 2 + c) * 64 + lane];
  }

  for (int t = t0; t < t1; ++t) {
    const int tb = tb0 + t;
    // vf loads (consumed after QK+exp -> latency covered)
    bf16x8 vf[8];
#pragma unroll
    for (int c = 0; c < 2; ++c)
#pragma unroll
      for (int ntd = 0; ntd < 4; ++ntd)
        vf[c * 4 + ntd] = VF8[(size_t)((tb * 2 + c) * 4 + ntd) * 64 + lane];

    // per-nt QK -> exp -> pw (klim trick: non-diag tiles never mask)
    const int klim = (t == ntiles - 1) ? 0 : (1 << 24);
#pragma unroll
    for (int nt = 0; nt < 4; ++nt) {
      f32x4 s0 = __builtin_amdgcn_mfma_f32_16x16x32_bf16(
          qf[0][0], kf[nt * 2 + 0], (f32x4)(0.f), 0, 0, 0);
      s0 = __builtin_amdgcn_mfma_f32_16x16x32_bf16(qf[0][1], kf[nt * 2 + 1],
                                                   s0, 0, 0, 0);
      f32x4 s1 = __builtin_amdgcn_mfma_f32_16x16x32_bf16(
          qf[1][0], kf[nt * 2 + 0], (f32x4)(0.f), 0, 0, 0);
      s1 = __builtin_amdgcn_mfma_f32_16x16x32_bf16(qf[1][1], kf[nt * 2 + 1],
                                                   s1, 0, 0, 0);
      const int key = t * 64 + nt * 16 + l15;
#pragma unroll
      for (int r = 0; r < 4; ++r) {
        const int q0 = s32 * 32 + quad * 4 + r + klim;
        const float p0 = (key <= q0) ? exp2f(fminf(s0[r], 44.f)) : 0.f;
        lsum[0][r] += p0;
        pw[wid][quad * 4 + r][nt * 16 + l15] = (bf16)p0;
        const float p1 = (key <= q0 + 16) ? exp2f(fminf(s1[r], 44.f)) : 0.f;
        lsum[1][r] += p1;
        pw[wid][16 + quad * 4 + r][nt * 16 + l15] = (bf16)p1;
      }
    }

    // prefetch next tile's kf into the same regs (last use was above)
    if (t + 1 < t1) {
      const int tbn = tb + 1;
#pragma unroll
      for (int nt = 0; nt < 4; ++nt)
#pragma unroll
        for (int c = 0; c < 2; ++c)
          kf[nt * 2 + c] = KF8[(size_t)((tbn * 4 + nt) * 2 + c) * 64 + lane];
    }

    // P C->A round-trip (same-wave LDS; lgkmcnt orders it), then PV
#pragma unroll
    for (int st = 0; st < 2; ++st) {
      const bf16x8 pf0 = *(const bf16x8*)&pw[wid][st * 16 + l15][quad * 8];
      const bf16x8 pf1 = *(const bf16x8*)&pw[wid][st * 16 + l15][32 + quad * 8];
#pragma unroll
      for (int ntd = 0; ntd < 4; ++ntd) {
        o[st][ntd] = __builtin_amdgcn_mfma_f32_16x16x32_bf16(
            pf0, vf[0 * 4 + ntd], o[st][ntd], 0, 0, 0);
        o[st][ntd] = __builtin_amdgcn_mfma_f32_16x16x32_bf16(
            pf1, vf[1 * 4 + ntd], o[st][ntd], 0, 0, 0);
      }
    }
  }

  // row sums across the 16 lanes of each quad
#pragma unroll
  for (int m = 1; m < 16; m <<= 1)
#pragma unroll
    for (int st = 0; st < 2; ++st)
#pragma unroll
      for (int r = 0; r < 4; ++r) lsum[st][r] += __shfl_xor(lsum[st][r], m, 64);

  const int slot = (b * 128 + s32) * 8 + e;
  if (l15 == 0) {
#pragma unroll
    for (int st = 0; st < 2; ++st)
#pragma unroll
      for (int r = 0; r < 4; ++r)
        lh[slot * 32 + st * 16 + quad * 4 + r] = lsum[st][r];
  }
#pragma unroll
  for (int st = 0; st < 2; ++st)
#pragma unroll
    for (int ntd = 0; ntd < 4; ++ntd)
#pragma unroll
      for (int r = 0; r < 4; ++r)
        Oh[(size_t)slot * 2048 + (st * 16 + quad * 4 + r) * 64 + ntd * 16 + l15] =
            (bf16)o[st][ntd][r];
}

// ---------------------------------------------------------------------------
// Sum the 8 eighth-partials and normalize.  262144 f32x4 -> grid 1024x256.
// ---------------------------------------------------------------------------
__global__ __launch_bounds__(256) void combine_kernel(
    const bf16* __restrict__ Oh, const float* __restrict__ lh,
    float* __restrict__ out) {
  const int gid = blockIdx.x * 256 + threadIdx.x;  // [0, 262144)
  const int token = gid >> 4;                      // 0..16383
  const int d4 = (gid & 15) * 4;
  const int b = token >> 12;
  const int s = token & 4095;
  const int s32 = s >> 5;
  const int qq = s & 31;
  const int slot0 = (b * 128 + s32) * 8;
  f32x4 acc = (f32x4)(0.f);
  float l = 0.f;
#pragma unroll
  for (int q = 0; q < 8; ++q) {
    const bf16x4 ov =
        *(const bf16x4*)(Oh + (size_t)(slot0 + q) * 2048 + qq * 64 + d4);
#pragma unroll
    for (int i = 0; i < 4; ++i) acc[i] += (float)ov[i];
    l += lh[(slot0 + q) * 32 + qq];
  }
  ((f32x4*)out)[gid] = acc * (1.f / l);
}

// ---------------------------------------------------------------------------
extern "C" void kernel_launch(void* const* d_in, const int* in_sizes, int n_in,
                              void* d_out, int out_size, void* d_ws,
                              size_t ws_size, hipStream_t stream) {
  const float* x  = (const float*)d_in[0];
  const float* Wq = (const float*)d_in[1];
  const float* bq = (const float*)d_in[2];
  const float* Wk = (const float*)d_in[3];
  const float* bk = (const float*)d_in[4];
  const float* Wv = (const float*)d_in[5];
  const float* bv = (const float*)d_in[6];
  float* out = (float*)d_out;

  char* ws = (char*)d_ws;
  bf16* Qs = (bf16*)(ws + QS_OFF);
  bf16* KF = (bf16*)(ws + KF_OFF);
  bf16* VF = (bf16*)(ws + VF_OFF);
  bf16* wp = (bf16*)(ws + WP_OFF);
  bf16* Oh = (bf16*)(ws + OP_OFF);
  float* lh = (float*)(ws + LP_OFF);

  wpack_kernel<<<768, 256, 0, stream>>>(Wq, Wk, Wv, wp);
  qkv_mfma_kernel<<<1024, 256, 0, stream>>>(x, bq, bk, bv, wp, Qs, KF, VF);
  attn_mfma_kernel<<<1024, 256, 0, stream>>>(Qs, KF, VF, Oh, lh);
  combine_kernel<<<1024, 256, 0, stream>>>(Oh, lh, out);
}